// Round 13
// baseline (1177.732 us; speedup 1.0000x reference)
//
#include <hip/hip_runtime.h>
#include <math.h>

// Dual-branch shifted-window self-attention — FUSED single kernel, both on MFMA.
// Blocks 0..1023:  branch 1: 16x16 windows, shift (8,8), ch 32..63 -> out 16..31.
//                  Round-11 verified body (vperm V layout, asm cvt_pk).
// Blocks 1024..2047: branch 0: 8x8 windows, no shift, ch 0..31 -> out 0..15.
//                  SAME T=256 body: each block = a 2x2 QUAD of 8x8 windows
//                  (one 16x16 pixel super-tile). Window-local attention is
//                  enforced by computing only BLOCK-DIAGONAL (chunk, m-tile)
//                  pairs: token's window = token>>6; chunk c covers window
//                  c>>1; m-tile M covers window M>>2. Each wave-half: 4 chunks
//                  x 4 m-bodies (16 of 64). The ones-column row-sum l then
//                  covers exactly the token's own window. All fragment algebra
//                  is byte-identical to the verified WS=16 path.
//
// Numerics (verified rounds 4/6/9/11): q pre-scaled by sqrt(1/ln2) so e^S =
// exp2(q'.q'^T) — bare v_exp_f32, no max subtraction. P = bf16_rne(exp2),
// used for BOTH numerator and ones-column row-sum l (self-normalizing).
// Q Dekker hi/lo; V bf16-RNE. Unnormalized P is symmetric: QK C-fragment of
// tile (s,t) IS the PV A-fragment of tile (t,s) under the shared K-slot
// placement lambda(g,j) = 16*(j>=4) + 4g + (j&3); V stored in LDS pre-permuted
// to lambda order with channel-row 4 = ones (V B-fragment = ONE ds_read_b128).
// cvt_pk stays INLINE ASM: round 12 showed __float22bfloat162_rn lowers to
// per-element software RNE (VGPR +4, dur +23%) — the asm is the fast path.

typedef __attribute__((ext_vector_type(4))) float f32x4;
typedef __attribute__((ext_vector_type(8))) short short8;

static constexpr int Ww = 256;
static constexpr int CIN = 64;
static constexpr int COUT = 32;
static constexpr size_t PLANE = 65536; // 256*256
static constexpr float ALPHA = 1.2011224087864498f; // sqrt(1/ln2)

__device__ inline float fexp2(float x) {
#if __has_builtin(__builtin_amdgcn_exp2f)
    return __builtin_amdgcn_exp2f(x);
#else
    float r;
    asm("v_exp_f32 %0, %1" : "=v"(r) : "v"(x));   // v_exp_f32 IS 2^x
    return r;
#endif
}

// pack two f32 -> one u32 of 2x bf16 (RNE), single instruction on gfx950
__device__ inline unsigned cvt_pk_bf16(float lo, float hi) {
    unsigned r;
    asm("v_cvt_pk_bf16_f32 %0, %1, %2" : "=v"(r) : "v"(lo), "v"(hi));
    return r;
}

__device__ inline unsigned short bfhi_u(float x) {   // truncation (Dekker hi)
    union { float f; unsigned u; } u; u.f = x;
    return (unsigned short)(u.u >> 16);
}
__device__ inline float bf2f(unsigned short h) {
    union { unsigned u; float f; } u; u.u = ((unsigned)h) << 16;
    return u.f;
}
__device__ inline unsigned short bf_rne(float x) {   // round-nearest-even bf16
    union { float f; unsigned u; } u; u.f = x;
    return (unsigned short)((u.u + 0x7FFFu + ((u.u >> 16) & 1u)) >> 16);
}

struct Smem16 {                                   // 31360 B
    unsigned short qpack[4][256][8];              // 16384
    unsigned short vperm[4][5][272];              // 10880 (row 544 B, 16B-aligned)
    float l_lds[4][256];                          // 4096
};

__global__ __launch_bounds__(512) void fused_attn(const float* __restrict__ x,
                                                  float* __restrict__ out) {
    __shared__ __align__(16) Smem16 smem;

    const int tid  = threadIdx.x;
    const int lane = tid & 63;
    const int wave = tid >> 6;
    const int head = wave >> 1;
    const int half = wave & 1;
    const int g = lane >> 4;
    const int n = lane & 15;
    const bool is16 = blockIdx.x < 1024;
    const int blk = is16 ? blockIdx.x : (blockIdx.x - 1024);
    const int wj = blk & 15, wi = (blk >> 4) & 15, b = blk >> 8;
    // win16: window origin (wi*16, wj*16), token (row,col) = (t>>4, t&15), shift 8.
    // quad8: super-tile origin (wi*16, wj*16); token t: quadrant q = t>>6,
    //        r = t&63 -> pixel (q>>1)*8 + (r>>3), (q&1)*8 + (r&7). No shift.

    // ---- global -> LDS; q * ALPHA then Dekker split; v bf16-RNE permuted.
#pragma unroll
    for (int k = 0; k < 16; ++k) {
        const int f = k * 512 + tid;
        const int c = f >> 8;            // 0..31
        const int t = f & 255;
        int gi, gj;
        if (is16) {
            gi = (wi * 16 + (t >> 4) + 248) & 255;   // src = rolled-8 mod 256
            gj = (wj * 16 + (t & 15) + 248) & 255;
        } else {
            const int q = t >> 6;
            gi = wi * 16 + (q >> 1) * 8 + ((t >> 3) & 7);
            gj = wj * 16 + (q & 1) * 8 + (t & 7);
        }
        const int cbase = is16 ? 32 : 0;
        float val = x[((size_t)b * CIN + cbase + c) * PLANE + (size_t)gi * Ww + gj];
        const int h = (c >> 2) & 3, ch = c & 3;
        if (c < 16) {
            val *= ALPHA;
            const unsigned short hi = bfhi_u(val);
            smem.qpack[h][t][ch]     = hi;
            smem.qpack[h][t][4 + ch] = bfhi_u(val - bf2f(hi));
        } else {
            // source s-offset rr = hi*16 + 4g + j  ->  pos = g*8 + hi*4 + j
            const int rr = t & 31;
            const int pos = (t & ~31) + ((rr >> 2) & 3) * 8 + (rr >> 4) * 4 + (rr & 3);
            smem.vperm[h][ch][pos] = bf_rne(val);
        }
    }
    // ones channel-row: read as K-slot data -> row sums l
#pragma unroll
    for (int k = 0; k < 2; ++k) {
        const int i = k * 512 + tid;
        smem.vperm[i >> 8][4][i & 255] = (unsigned short)0x3F80;
    }
    __syncthreads();

    const int tbase = half * 128;

    const unsigned long long m0  = (g == 0) ? ~0ull : 0ull;
    const unsigned long long m1  = (g == 1) ? ~0ull : 0ull;
    const unsigned long long m01 = (g <  2) ? ~0ull : 0ull;

    // QK K-slot placement: A:[s_hi(g0) s_hi(g1) 0 0 | s_lo(g0) 0 0 0]
    //                      B:[t_hi(g0) t_lo(g1) 0 0 | t_hi(g0) 0 0 0]
    short8 BQ[8];
#pragma unroll
    for (int m = 0; m < 8; ++m) {
        union { short8 v; unsigned long long q[2]; } u, f;
        u.v = *(const short8*)&smem.qpack[head][tbase + m * 16 + n][0];
        f.q[0] = (u.q[0] & m0) | (u.q[1] & m1);
        f.q[1] = u.q[0] & m0;
        BQ[m] = f.v;
    }

    f32x4 O[8];
#pragma unroll
    for (int m = 0; m < 8; ++m) O[m] = (f32x4){0.f, 0.f, 0.f, 0.f};
    const f32x4 zero4 = (f32x4){0.f, 0.f, 0.f, 0.f};

    // win16: 8 chunks x all 8 m-tiles. quad8: 4 chunks (this half's windows)
    // x the 4 diagonal m-tiles each.
    const int ncc = is16 ? 8 : 4;
    for (int cc = 0; cc < ncc; ++cc) {
        const int c = is16 ? cc : (half * 4 + cc);   // global s-chunk
        short8 AQ[2];
#pragma unroll
        for (int a = 0; a < 2; ++a) {
            union { short8 v; unsigned long long q[2]; } u, f;
            u.v = *(const short8*)&smem.qpack[head][c * 32 + a * 16 + n][0];
            f.q[0] = u.q[0] & m01;
            f.q[1] = u.q[1] & m0;
            AQ[a] = f.v;
        }

        // V B-fragment: pre-permuted -> one 16B read (rows 0..3 data, 4 ones)
        short8 Vhf = {0, 0, 0, 0, 0, 0, 0, 0};
        if (n < 5) Vhf = *(const short8*)&smem.vperm[head][n][c * 32 + g * 8];

        const int mb = is16 ? 0 : ((cc >> 1) * 4);   // diagonal m-tile base
        const int nm = is16 ? 8 : 4;
#pragma unroll 4
        for (int mi = 0; mi < nm; ++mi) {
            const int m = mb + mi;
            const f32x4 c0 = __builtin_amdgcn_mfma_f32_16x16x32_bf16(AQ[0], BQ[m], zero4, 0, 0, 0);
            const f32x4 c1 = __builtin_amdgcn_mfma_f32_16x16x32_bf16(AQ[1], BQ[m], zero4, 0, 0, 0);
            union { unsigned u[4]; short8 s; } pk;
            pk.u[0] = cvt_pk_bf16(fexp2(c0[0]), fexp2(c0[1]));
            pk.u[1] = cvt_pk_bf16(fexp2(c0[2]), fexp2(c0[3]));
            pk.u[2] = cvt_pk_bf16(fexp2(c1[0]), fexp2(c1[1]));
            pk.u[3] = cvt_pk_bf16(fexp2(c1[2]), fexp2(c1[3]));
            O[m] = __builtin_amdgcn_mfma_f32_16x16x32_bf16(pk.s, Vhf, O[m], 0, 0, 0);
        }
    }

    // ---- normalize: O column 4 = l[token]; publish 1/l via LDS (wave-local;
    // DS ops are wave-ordered, writer and reader lanes are in the same wave).
    if (n == 4) {
#pragma unroll
        for (int m = 0; m < 8; ++m)
#pragma unroll
            for (int r = 0; r < 4; ++r)
                smem.l_lds[head][tbase + m * 16 + 4 * g + r] = __builtin_amdgcn_rcpf(O[m][r]);
    }
    if (n < 4) {
        const int obase = is16 ? 16 : 0;
        float* op = out + ((size_t)b * COUT + obase + head * 4 + n) * PLANE;
#pragma unroll
        for (int m = 0; m < 8; ++m) {
            const int token = tbase + m * 16 + 4 * g;
            const f32x4 inv4 = *(const f32x4*)&smem.l_lds[head][token];
            int gi, gj0;
            if (is16) {
                gi  = (wi * 16 + (token >> 4) + 248) & 255;
                gj0 = (wj * 16 + (token & 15) + 248) & 255; // mult of 4: no wrap in float4
            } else {
                const int q = token >> 6;
                gi  = wi * 16 + (q >> 1) * 8 + ((token >> 3) & 7);
                gj0 = wj * 16 + (q & 1) * 8 + (token & 7);  // 0 or 4: float4 stays in row
            }
            f32x4 res;
            res[0] = O[m][0] * inv4[0];
            res[1] = O[m][1] * inv4[1];
            res[2] = O[m][2] * inv4[2];
            res[3] = O[m][3] * inv4[3];
            *(f32x4*)(op + (size_t)gi * Ww + gj0) = res;
        }
    }
}

extern "C" void kernel_launch(void* const* d_in, const int* in_sizes, int n_in,
                              void* d_out, int out_size, void* d_ws, size_t ws_size,
                              hipStream_t stream) {
    const float* x = (const float*)d_in[0];
    float* out = (float*)d_out;

    // blocks 0..1023: win16 (heavier, dispatched first);
    // blocks 1024..2047: quad-of-8x8 windows (same T=256 body, diagonal tiles).
    hipLaunchKernelGGL(fused_attn, dim3(2048), dim3(512), 0, stream, x, out);
}

// Round 15
// 62.778 us; speedup vs baseline: 18.7602x; 18.7602x over previous
//
#include <hip/hip_runtime.h>
#include <math.h>

// Dual-branch shifted-window self-attention — FUSED single kernel.
// Blocks 0..1023:  branch 1 (16x16 windows, shift (8,8), ch 32..63 -> out 16..31),
//                  MFMA body + V pre-permuted LDS layout (round-11 verified),
//                  with the m-loop 2-wide interleaved (ONLY change this round).
// Blocks 1024..3071: branch 0 (8x8 windows, no shift, ch 0..31 -> out 0..15),
//                  fp32 vector body verbatim (round-9 verified), 8 independent
//                  waves per block (wave-private LDS slices, no barrier).
//
// Round-15 change (single, isolated): win16 m-loop processes (m, m+1) pairs —
// all 4 QK MFMAs issue before either exp/cvt/PV chain, giving the scheduler
// explicit ILP so MFMA latency hides under the sibling's exp chain. cvt_pk
// stays INLINE ASM (round 12 proved __float22bfloat162_rn lowers to software
// RNE and cost +23%; the asm single-instruction pack is the fast path).
//
// Numerics (verified rounds 4/6/9/11): q pre-scaled by sqrt(1/ln2) so e^S =
// exp2(q'.q'^T) — bare v_exp_f32, no max subtraction. P = bf16_rne(exp2),
// used for BOTH numerator and ones-column row-sum l (self-normalizing).
// Q Dekker hi/lo; V bf16-RNE. Unnormalized P is symmetric: QK C-fragment of
// tile (s,t) IS the PV A-fragment of tile (t,s) under the shared K-slot
// placement lambda(g,j) = 16*(j>=4) + 4g + (j&3); V stored in LDS pre-permuted
// to lambda order with channel-row 4 = ones (V B-fragment = ONE ds_read_b128).

typedef __attribute__((ext_vector_type(4))) float f32x4;
typedef __attribute__((ext_vector_type(8))) short short8;

static constexpr int Ww = 256;
static constexpr int CIN = 64;
static constexpr int COUT = 32;
static constexpr size_t PLANE = 65536; // 256*256
static constexpr float ALPHA = 1.2011224087864498f; // sqrt(1/ln2)

__device__ inline float fexp2(float x) {
#if __has_builtin(__builtin_amdgcn_exp2f)
    return __builtin_amdgcn_exp2f(x);
#else
    float r;
    asm("v_exp_f32 %0, %1" : "=v"(r) : "v"(x));   // v_exp_f32 IS 2^x
    return r;
#endif
}

// pack two f32 -> one u32 of 2x bf16 (RNE), single instruction on gfx950
__device__ inline unsigned cvt_pk_bf16(float lo, float hi) {
    unsigned r;
    asm("v_cvt_pk_bf16_f32 %0, %1, %2" : "=v"(r) : "v"(lo), "v"(hi));
    return r;
}

__device__ inline unsigned short bfhi_u(float x) {   // truncation (Dekker hi)
    union { float f; unsigned u; } u; u.f = x;
    return (unsigned short)(u.u >> 16);
}
__device__ inline float bf2f(unsigned short h) {
    union { unsigned u; float f; } u; u.u = ((unsigned)h) << 16;
    return u.f;
}
__device__ inline unsigned short bf_rne(float x) {   // round-nearest-even bf16
    union { float f; unsigned u; } u; u.f = x;
    return (unsigned short)((u.u + 0x7FFFu + ((u.u >> 16) & 1u)) >> 16);
}

struct Smem16 {                                   // 31360 B (win16 path)
    unsigned short qpack[4][256][8];              // 16384
    unsigned short vperm[4][5][272];              // 10880 (row 544 B, 16B-aligned)
    float l_lds[4][256];                          // 4096
};
struct Smem8 {                                    // 16384 B (win8 path)
    float4 qs[8][64];
    float4 vs[8][64];
};
union SmemU { Smem16 a; Smem8 b; };

__global__ __launch_bounds__(512) void fused_attn(const float* __restrict__ x,
                                                  float* __restrict__ out) {
    __shared__ __align__(16) SmemU smem;

    const int tid  = threadIdx.x;
    const int lane = tid & 63;
    const int wave = tid >> 6;

    if (blockIdx.x < 1024) {
        // ================= branch 1: 16x16, shift (8,8), MFMA ================
        const int blk = blockIdx.x;
        const int wj = blk & 15, wi = (blk >> 4) & 15, b = blk >> 8;
        const int head = wave >> 1;
        const int half = wave & 1;
        const int g = lane >> 4;
        const int n = lane & 15;

        // ---- global -> LDS; q * ALPHA then Dekker split; v bf16-RNE permuted.
#pragma unroll
        for (int k = 0; k < 16; ++k) {
            const int f = k * 512 + tid;
            const int c = f >> 8;            // 0..31
            const int t = f & 255;
            const int gi = (wi * 16 + (t >> 4) + 248) & 255;   // src = rolled-8 mod 256
            const int gj = (wj * 16 + (t & 15) + 248) & 255;
            float val = x[((size_t)b * CIN + 32 + c) * PLANE + (size_t)gi * Ww + gj];
            const int h = (c >> 2) & 3, ch = c & 3;
            if (c < 16) {
                val *= ALPHA;
                const unsigned short hi = bfhi_u(val);
                smem.a.qpack[h][t][ch]     = hi;
                smem.a.qpack[h][t][4 + ch] = bfhi_u(val - bf2f(hi));
            } else {
                // source s-offset rr = hi*16 + 4g + j  ->  pos = g*8 + hi*4 + j
                const int rr = t & 31;
                const int pos = (t & ~31) + ((rr >> 2) & 3) * 8 + (rr >> 4) * 4 + (rr & 3);
                smem.a.vperm[h][ch][pos] = bf_rne(val);
            }
        }
        // ones channel-row: read as K-slot data -> row sums l
#pragma unroll
        for (int k = 0; k < 2; ++k) {
            const int i = k * 512 + tid;
            smem.a.vperm[i >> 8][4][i & 255] = (unsigned short)0x3F80;
        }
        __syncthreads();

        const int tbase = half * 128;

        const unsigned long long m0  = (g == 0) ? ~0ull : 0ull;
        const unsigned long long m1  = (g == 1) ? ~0ull : 0ull;
        const unsigned long long m01 = (g <  2) ? ~0ull : 0ull;

        // QK K-slot placement: A:[s_hi(g0) s_hi(g1) 0 0 | s_lo(g0) 0 0 0]
        //                      B:[t_hi(g0) t_lo(g1) 0 0 | t_hi(g0) 0 0 0]
        short8 BQ[8];
#pragma unroll
        for (int m = 0; m < 8; ++m) {
            union { short8 v; unsigned long long q[2]; } u, f;
            u.v = *(const short8*)&smem.a.qpack[head][tbase + m * 16 + n][0];
            f.q[0] = (u.q[0] & m0) | (u.q[1] & m1);
            f.q[1] = u.q[0] & m0;
            BQ[m] = f.v;
        }

        f32x4 O[8];
#pragma unroll
        for (int m = 0; m < 8; ++m) O[m] = (f32x4){0.f, 0.f, 0.f, 0.f};
        const f32x4 zero4 = (f32x4){0.f, 0.f, 0.f, 0.f};

        for (int c = 0; c < 8; ++c) {                 // s-chunks of 32
            short8 AQ[2];
#pragma unroll
            for (int a = 0; a < 2; ++a) {
                union { short8 v; unsigned long long q[2]; } u, f;
                u.v = *(const short8*)&smem.a.qpack[head][c * 32 + a * 16 + n][0];
                f.q[0] = u.q[0] & m01;
                f.q[1] = u.q[1] & m0;
                AQ[a] = f.v;
            }

            // V B-fragment: pre-permuted -> one 16B read (rows 0..3 data, 4 ones)
            short8 Vhf = {0, 0, 0, 0, 0, 0, 0, 0};
            if (n < 5) Vhf = *(const short8*)&smem.a.vperm[head][n][c * 32 + g * 8];

            // 2-wide m interleave: 4 QK MFMAs issue before either exp/cvt/PV
            // chain (m-bodies independent; sibling exp hides MFMA latency).
#pragma unroll
            for (int mm = 0; mm < 8; mm += 2) {
                const f32x4 a0 = __builtin_amdgcn_mfma_f32_16x16x32_bf16(AQ[0], BQ[mm],     zero4, 0, 0, 0);
                const f32x4 a1 = __builtin_amdgcn_mfma_f32_16x16x32_bf16(AQ[1], BQ[mm],     zero4, 0, 0, 0);
                const f32x4 b0 = __builtin_amdgcn_mfma_f32_16x16x32_bf16(AQ[0], BQ[mm + 1], zero4, 0, 0, 0);
                const f32x4 b1 = __builtin_amdgcn_mfma_f32_16x16x32_bf16(AQ[1], BQ[mm + 1], zero4, 0, 0, 0);

                union { unsigned u[4]; short8 s; } pkA, pkB;
                pkA.u[0] = cvt_pk_bf16(fexp2(a0[0]), fexp2(a0[1]));
                pkA.u[1] = cvt_pk_bf16(fexp2(a0[2]), fexp2(a0[3]));
                pkA.u[2] = cvt_pk_bf16(fexp2(a1[0]), fexp2(a1[1]));
                pkA.u[3] = cvt_pk_bf16(fexp2(a1[2]), fexp2(a1[3]));
                pkB.u[0] = cvt_pk_bf16(fexp2(b0[0]), fexp2(b0[1]));
                pkB.u[1] = cvt_pk_bf16(fexp2(b0[2]), fexp2(b0[3]));
                pkB.u[2] = cvt_pk_bf16(fexp2(b1[0]), fexp2(b1[1]));
                pkB.u[3] = cvt_pk_bf16(fexp2(b1[2]), fexp2(b1[3]));

                O[mm]     = __builtin_amdgcn_mfma_f32_16x16x32_bf16(pkA.s, Vhf, O[mm],     0, 0, 0);
                O[mm + 1] = __builtin_amdgcn_mfma_f32_16x16x32_bf16(pkB.s, Vhf, O[mm + 1], 0, 0, 0);
            }
        }

        if (n == 4) {
#pragma unroll
            for (int m = 0; m < 8; ++m)
#pragma unroll
                for (int r = 0; r < 4; ++r)
                    smem.a.l_lds[head][tbase + m * 16 + 4 * g + r] = __builtin_amdgcn_rcpf(O[m][r]);
        }
        if (n < 4) {
            float* op = out + ((size_t)b * COUT + 16 + head * 4 + n) * PLANE;
#pragma unroll
            for (int m = 0; m < 8; ++m) {
                const f32x4 inv4 = *(const f32x4*)&smem.a.l_lds[head][tbase + m * 16 + 4 * g];
                const int gi  = (wi * 16 + half * 8 + m + 248) & 255;
                const int gj0 = (wj * 16 + 4 * g + 248) & 255;
                f32x4 res;
                res[0] = O[m][0] * inv4[0];
                res[1] = O[m][1] * inv4[1];
                res[2] = O[m][2] * inv4[2];
                res[3] = O[m][3] * inv4[3];
                *(f32x4*)(op + (size_t)gi * Ww + gj0) = res;
            }
        }
    } else {
        // ============ branch 0: 8x8, no shift, fp32 vector (round-9 verbatim) =
        int bid = (blockIdx.x - 1024) * 8 + wave;   // 0..16383
        const int wj   = bid & 31; bid >>= 5;
        const int wi   = bid & 31; bid >>= 5;
        const int head = bid & 3;  bid >>= 2;
        const int b    = bid;

        const int t  = lane;
        const int gi = wi * 8 + (t >> 3);
        const int gj = wj * 8 + (t & 7);
        const size_t pix = (size_t)gi * Ww + gj;

        const float* xq = x + (size_t)b * CIN * PLANE + (size_t)(head * 4) * PLANE + pix;
        const float* xv = xq + 16 * PLANE;

        float4* qs = smem.b.qs[wave];
        float4* vs = smem.b.vs[wave];

        float4 q, v;
        q.x = xq[0] * ALPHA; q.y = xq[PLANE] * ALPHA;
        q.z = xq[2 * PLANE] * ALPHA; q.w = xq[3 * PLANE] * ALPHA;
        v.x = xv[0];         v.y = xv[PLANE];     v.z = xv[2 * PLANE]; v.w = xv[3 * PLANE];
        qs[t] = q;
        vs[t] = v;
        // no barrier: qs/vs slices are wave-private; DS pipe is in-order per wave.

        float l = 0.f;
        float4 acc = make_float4(0.f, 0.f, 0.f, 0.f);
#pragma unroll
        for (int s = 0; s < 64; ++s) {
            const float4 p = qs[s];
            const float d = q.x * p.x + q.y * p.y + q.z * p.z + q.w * p.w;
            const float e = fexp2(d);
            l += e;
            const float4 vv = vs[s];
            acc.x += e * vv.x; acc.y += e * vv.y;
            acc.z += e * vv.z; acc.w += e * vv.w;
        }
        const float inv = 1.0f / l;

        float* ob = out + (size_t)b * COUT * PLANE + (size_t)(head * 4) * PLANE + pix;
        ob[0]         = acc.x * inv;
        ob[PLANE]     = acc.y * inv;
        ob[2 * PLANE] = acc.z * inv;
        ob[3 * PLANE] = acc.w * inv;
    }
}

extern "C" void kernel_launch(void* const* d_in, const int* in_sizes, int n_in,
                              void* d_out, int out_size, void* d_ws, size_t ws_size,
                              hipStream_t stream) {
    const float* x = (const float*)d_in[0];
    float* out = (float*)d_out;

    // blocks 0..1023: win16 (long pole, dispatched first);
    // blocks 1024..3071: win8 (16384 window-heads / 8 waves per block).
    hipLaunchKernelGGL(fused_attn, dim3(3072), dim3(512), 0, stream, x, out);
}